// Round 1
// 376.975 us; speedup vs baseline: 1.0026x; 1.0026x over previous
//
#include <hip/hip_runtime.h>

// ExtractGraph: maxpool(2x2) -> threshold=(max-min)/96 -> d=pool+noise ->
// diagonal-neighbor adjacency (|diff|<=thr), symmetric -> & dropout_mask ->
// row-major COO edge list padded with sentinel NUM_NODES.
//
// R3: flags stage re-gridded one-thread-per-candidate-edge (144 blocks x 256),
// collapsing the serialized 4-round scattered mask gather of the per-node
// version into a single predicated load round with 4x the waves. Per-node
// 4-bit flags reassembled via __ballot (4 consecutive lanes = 1 node).
// k_pool / k_write keep the verified R2 structure; k_write's cross-block
// prefix widens from 36 to 144 per-edge-block counts (uniform scalar loads).

#define HW 192
#define MM 96
#define NUM_NODES 9216
#define MAX_EDGES 36864
#define NBP 36    // pool/write grid: 1 node/thread
#define NBF 144   // flags grid: 1 candidate edge/thread
#define BT 256

// ws layout (4-byte words):
//   [0,     9216)  d_buf   (float)  pooled + noise
//   [9216,  9252)  blk_max (float)  per-pool-block max
//   [9252,  9288)  blk_min (float)  per-pool-block min
//   [9288, 18504)  flags   (int)    per-node 4-bit neighbor flags
//   [18504,18648)  blk_cnt (int)    per-edge-block pass counts (144)

__global__ __launch_bounds__(BT) void k_pool(
    const float* __restrict__ dc,
    const float* __restrict__ noise,
    float* __restrict__ d_buf,
    float* __restrict__ blk_max,
    float* __restrict__ blk_min)
{
    const int t = threadIdx.x;
    const int l = blockIdx.x * BT + t;
    const int i = l / MM, j = l - i * MM;
    const float* r0 = dc + (2 * i) * HW + 2 * j;
    float2 a = *(const float2*)r0;
    float2 b = *(const float2*)(r0 + HW);
    float p = fmaxf(fmaxf(a.x, a.y), fmaxf(b.x, b.y));
    d_buf[l] = p + noise[l];   // noise added AFTER threshold stats (on p)

    float mx = p, mn = p;
    #pragma unroll
    for (int off = 32; off > 0; off >>= 1) {
        mx = fmaxf(mx, __shfl_down(mx, off, 64));
        mn = fminf(mn, __shfl_down(mn, off, 64));
    }
    __shared__ float smx[4], smn[4];
    const int lane = t & 63, wid = t >> 6;
    if (lane == 0) { smx[wid] = mx; smn[wid] = mn; }
    __syncthreads();
    if (t == 0) {
        blk_max[blockIdx.x] = fmaxf(fmaxf(smx[0], smx[1]), fmaxf(smx[2], smx[3]));
        blk_min[blockIdx.x] = fminf(fminf(smn[0], smn[1]), fminf(smn[2], smn[3]));
    }
}

__global__ __launch_bounds__(BT) void k_flags(
    const float* __restrict__ d_buf,
    const float* __restrict__ blk_max,
    const float* __restrict__ blk_min,
    const int*   __restrict__ mask,
    int* __restrict__ flags,
    int* __restrict__ blk_cnt)
{
    __shared__ float s_thr;
    const int t = threadIdx.x;
    if (t < 64) {
        float mx = (t < NBP) ? blk_max[t] : -3.0e38f;
        float mn = (t < NBP) ? blk_min[t] :  3.0e38f;
        #pragma unroll
        for (int off = 32; off > 0; off >>= 1) {
            mx = fmaxf(mx, __shfl_down(mx, off, 64));
            mn = fminf(mn, __shfl_down(mn, off, 64));
        }
        if (t == 0) s_thr = (mx - mn) / 96.0f;
    }
    __syncthreads();
    const float thr = s_thr;

    // one thread per candidate edge: e = 4*node + q
    const int e = blockIdx.x * BT + t;
    const int l = e >> 2, q = e & 3;
    const int i = l / MM, j = l - i * MM;
    // q: 0->(-1,-1) off -97 ; 1->(-1,+1) off -95 ; 2->(+1,-1) off +95 ; 3->(+1,+1) off +97
    const int dy = (q & 2) ? 1 : -1;
    const int dx = (q & 1) ? 1 : -1;
    const int nb = l + dy * MM + dx;
    const bool ok = ((q & 2) ? (i < MM - 1) : (i > 0)) &&
                    ((q & 1) ? (j < MM - 1) : (j > 0));
    bool pass = false;
    if (ok) {
        const float diff = fabsf(d_buf[nb] - d_buf[l]);   // d_buf: 36 KB, L2-hit
        if (diff <= thr)
            pass = mask[(size_t)l * NUM_NODES + nb] != 0; // single scattered round
    }
    const unsigned long long bal = __ballot(pass);
    const int lane = t & 63, wid = t >> 6;
    if ((lane & 3) == 0)
        flags[l] = (int)((bal >> (lane & 60)) & 0xFull);  // bit q of node l

    __shared__ int sc[4];
    if (lane == 0) sc[wid] = __popcll(bal);
    __syncthreads();
    if (t == 0) blk_cnt[blockIdx.x] = sc[0] + sc[1] + sc[2] + sc[3];
}

__global__ __launch_bounds__(BT) void k_write(
    const int* __restrict__ flags,
    const int* __restrict__ blk_cnt,
    int* __restrict__ out)
{
    const int t = threadIdx.x, b = blockIdx.x;

    // 144-entry prefix: uniform (scalar) L2 loads, every thread.
    // k_write block b covers nodes [256b, 256b+256) = edge-blocks [4b, 4b+4).
    int blkoff = 0, total = 0;
    #pragma unroll 8
    for (int k = 0; k < NBF; ++k) {
        int c = blk_cnt[k];
        if (k < 4 * b) blkoff += c;
        total += c;
    }

    const int l = b * BT + t;
    const int f = flags[l];
    const int c = __popc(f);

    // inclusive wave scan, then cross-wave offsets via LDS
    int inc = c;
    const int lane = t & 63, wid = t >> 6;
    #pragma unroll
    for (int off = 1; off < 64; off <<= 1) {
        int v = __shfl_up(inc, off, 64);
        if (lane >= off) inc += v;
    }
    __shared__ int wtot[4];
    if (lane == 63) wtot[wid] = inc;
    __syncthreads();
    int wpre = 0;
    for (int k = 0; k < wid; ++k) wpre += wtot[k];

    int pos = blkoff + wpre + (inc - c);   // global exclusive prefix
    if (f & 1) { out[pos] = l; out[MAX_EDGES + pos] = l - 97; ++pos; }
    if (f & 2) { out[pos] = l; out[MAX_EDGES + pos] = l - 95; ++pos; }
    if (f & 4) { out[pos] = l; out[MAX_EDGES + pos] = l + 95; ++pos; }
    if (f & 8) { out[pos] = l; out[MAX_EDGES + pos] = l + 97; ++pos; }

    // sentinel tail, grid-strided across all 9216 threads
    for (int idx = total + b * BT + t; idx < MAX_EDGES; idx += NUM_NODES) {
        out[idx] = NUM_NODES;
        out[MAX_EDGES + idx] = NUM_NODES;
    }
}

extern "C" void kernel_launch(void* const* d_in, const int* in_sizes, int n_in,
                              void* d_out, int out_size, void* d_ws, size_t ws_size,
                              hipStream_t stream) {
    const float* d_coarse = (const float*)d_in[0];
    const float* noise    = (const float*)d_in[1];
    const int*   mask     = (const int*)d_in[2];
    int* out = (int*)d_out;

    float* ws      = (float*)d_ws;
    float* d_buf   = ws;
    float* blk_max = ws + 9216;
    float* blk_min = ws + 9252;
    int*   flags   = (int*)(ws + 9288);
    int*   blk_cnt = (int*)(ws + 18504);

    k_pool <<<NBP, BT, 0, stream>>>(d_coarse, noise, d_buf, blk_max, blk_min);
    k_flags<<<NBF, BT, 0, stream>>>(d_buf, blk_max, blk_min, mask, flags, blk_cnt);
    k_write<<<NBP, BT, 0, stream>>>(flags, blk_cnt, out);
}